// Round 8
// baseline (660.874 us; speedup 1.0000x reference)
//
#include <hip/hip_runtime.h>

#define N_NODES 100000
#define N_EDGES 1600000
#define TOT (N_EDGES + N_NODES)
#define IN_CH 256
#define NHEAD 4
#define CH 64
#define HC 256
#define NEG_SLOPE 0.2f

typedef _Float16 half8 __attribute__((ext_vector_type(8)));
typedef _Float16 h2v __attribute__((ext_vector_type(2)));
typedef float f32x4 __attribute__((ext_vector_type(4)));
typedef unsigned short ushort_t;
typedef unsigned int uint_t;

static __device__ __forceinline__ ushort_t f2h(float f) {
  _Float16 h = (_Float16)f;
  return __builtin_bit_cast(ushort_t, h);
}

// ---------------- W fp32 [K=256][N=256] -> Wt_arr, MFMA-fragment-major ----------------
// uint4 index f = (ks*16 + n)*64 + lane ; halfs j=0..7 :
//   W[ ks*32 + (lane>>4)*8 + j ][ n*16 + (lane&15) ]
// so the GEMM's B-fragment ds_read is linear in lane (conflict-free) and staging is memcpy.
__global__ __launch_bounds__(256) void conv_w(const float* __restrict__ W,
                                              uint4* __restrict__ Wt_arr) {
  int id = blockIdx.x * 256 + threadIdx.x;  // 0..8191
  int lane = id & 63;
  int n = (id >> 6) & 15;
  int ks = id >> 10;
  int col = n * 16 + (lane & 15);
  int kbase = ks * 32 + (lane >> 4) * 8;
  ushort_t h[8];
#pragma unroll
  for (int j = 0; j < 8; ++j) h[j] = f2h(W[(size_t)(kbase + j) * HC + col]);
  uint4 u;
  u.x = (uint_t)h[0] | ((uint_t)h[1] << 16);
  u.y = (uint_t)h[2] | ((uint_t)h[3] << 16);
  u.z = (uint_t)h[4] | ((uint_t)h[5] << 16);
  u.w = (uint_t)h[6] | ((uint_t)h[7] << 16);
  Wt_arr[id] = u;
}

// ---------------- MFMA GEMM: whole B in LDS, persistent blocks ----------------
// 1024 threads = 16 waves; each wave: 16 rows x 256 cols. Stripe = 256 rows.
#define NSTRIPES ((N_NODES + 255) / 256)  // 391

__global__ __launch_bounds__(1024, 4) void gemm_mfma(const float* __restrict__ X,
                                                     const uint4* __restrict__ Wt_arr,
                                                     const float* __restrict__ att_src,
                                                     const float* __restrict__ att_dst,
                                                     uint2* __restrict__ Hmp,
                                                     float* __restrict__ as_out,
                                                     float* __restrict__ ad_out, int M) {
  __shared__ uint4 Bs[8192];  // 128 KB: [ks][n][lane]
  const int tid = threadIdx.x;
  const int lane = tid & 63;
  const int wid = tid >> 6;   // 0..15
  const int l16 = lane & 15;
  const int lhi = lane >> 4;  // 0..3

  // stage whole Wt (linear copy, 8 uint4 per thread)
  {
    uint4 v[8];
#pragma unroll
    for (int i = 0; i < 8; ++i) v[i] = Wt_arr[i * 1024 + tid];
#pragma unroll
    for (int i = 0; i < 8; ++i) Bs[i * 1024 + tid] = v[i];
  }
  __syncthreads();

  for (int s = blockIdx.x; s < NSTRIPES; s += 256) {
    const int srow0 = s * 256;
    int rowA = srow0 + wid * 16 + l16;
    int rowA_c = rowA < M ? rowA : M - 1;
    const float4* __restrict__ xrow4 =
        reinterpret_cast<const float4*>(X + (size_t)rowA_c * IN_CH + lhi * 8);

    f32x4 acc[16] = {};

    float4 xa = xrow4[0];
    float4 xb = xrow4[1];
#pragma unroll
    for (int ks = 0; ks < 8; ++ks) {
      float4 na, nb;
      if (ks < 7) {                 // prefetch next k-step (hidden under MFMAs)
        na = xrow4[(ks + 1) * 8];   // float4 units: k-step stride = 32 floats = 8 float4
        nb = xrow4[(ks + 1) * 8 + 1];
      }
      uint4 ua;
      ua.x = __builtin_bit_cast(uint_t, __builtin_amdgcn_cvt_pkrtz(xa.x, xa.y));
      ua.y = __builtin_bit_cast(uint_t, __builtin_amdgcn_cvt_pkrtz(xa.z, xa.w));
      ua.z = __builtin_bit_cast(uint_t, __builtin_amdgcn_cvt_pkrtz(xb.x, xb.y));
      ua.w = __builtin_bit_cast(uint_t, __builtin_amdgcn_cvt_pkrtz(xb.z, xb.w));
      half8 a = __builtin_bit_cast(half8, ua);
#pragma unroll
      for (int n = 0; n < 16; ++n) {
        half8 b = *reinterpret_cast<const half8*>(&Bs[(ks * 16 + n) * 64 + lane]);
        acc[n] = __builtin_amdgcn_mfma_f32_16x16x32_f16(a, b, acc[n], 0, 0, 0);
      }
      xa = na; xb = nb;
    }

    // epilogue: pack Hmp + fused attention dots (att vectors loaded here to keep
    // the k-loop register footprint under the 128-VGPR / 4-waves-per-EU cap)
    float attS[16], attD[16];
#pragma unroll
    for (int n = 0; n < 16; ++n) {
      attS[n] = att_src[n * 16 + l16];
      attD[n] = att_dst[n * 16 + l16];
    }

#pragma unroll
    for (int r = 0; r < 4; ++r) {
      int grow = srow0 + wid * 16 + lhi * 4 + r;
      if (grow < M) {
#pragma unroll
        for (int n2 = 0; n2 < 4; ++n2) {
          uint_t pk01 = __builtin_bit_cast(uint_t,
              __builtin_amdgcn_cvt_pkrtz(acc[n2][r], acc[n2 + 4][r]));
          uint_t pk23 = __builtin_bit_cast(uint_t,
              __builtin_amdgcn_cvt_pkrtz(acc[n2 + 8][r], acc[n2 + 12][r]));
          Hmp[(size_t)grow * 64 + n2 * 16 + l16] = make_uint2(pk01, pk23);
        }
        float sv[4] = {0.f, 0.f, 0.f, 0.f}, dv[4] = {0.f, 0.f, 0.f, 0.f};
#pragma unroll
        for (int h = 0; h < 4; ++h)
#pragma unroll
          for (int j = 0; j < 4; ++j) {
            sv[h] += acc[h * 4 + j][r] * attS[h * 4 + j];
            dv[h] += acc[h * 4 + j][r] * attD[h * 4 + j];
          }
#pragma unroll
        for (int off = 1; off < 16; off <<= 1)
#pragma unroll
          for (int h = 0; h < 4; ++h) {
            sv[h] += __shfl_xor(sv[h], off, 16);
            dv[h] += __shfl_xor(dv[h], off, 16);
          }
        if (l16 == 0) {
#pragma unroll
          for (int h = 0; h < 4; ++h) {
            as_out[(size_t)grow * 4 + h] = sv[h];
            ad_out[(size_t)grow * 4 + h] = dv[h];
          }
        }
      }
    }
  }
}

// ---------------- CSR build ----------------
__global__ __launch_bounds__(256) void count_deg(const int* __restrict__ edst,
                                                 int* __restrict__ deg) {
  int t = blockIdx.x * 256 + threadIdx.x;
  if (t >= N_EDGES / 4) return;
  int4 d4 = reinterpret_cast<const int4*>(edst)[t];
  atomicAdd(&deg[d4.x], 1);
  atomicAdd(&deg[d4.y], 1);
  atomicAdd(&deg[d4.z], 1);
  atomicAdd(&deg[d4.w], 1);
}

// scan1 adds the +1 self-loop per node inline.
__global__ __launch_bounds__(256) void scan1(const int* __restrict__ deg,
                                             int* __restrict__ rp,
                                             int* __restrict__ bsum) {
  __shared__ int sh[256];
  int t = threadIdx.x;
  int base = blockIdx.x * 1024 + t * 4;
  int v[4];
#pragma unroll
  for (int i = 0; i < 4; ++i) v[i] = (base + i < N_NODES) ? (deg[base + i] + 1) : 0;
  int tsum = v[0] + v[1] + v[2] + v[3];
  sh[t] = tsum;
  __syncthreads();
  for (int off = 1; off < 256; off <<= 1) {
    int x = (t >= off) ? sh[t - off] : 0;
    __syncthreads();
    sh[t] += x;
    __syncthreads();
  }
  if (t == 255) bsum[blockIdx.x] = sh[255];
  int run = sh[t] - tsum;
#pragma unroll
  for (int i = 0; i < 4; ++i) {
    if (base + i < N_NODES) rp[base + i] = run;
    run += v[i];
  }
}

#define NBLK1 ((N_NODES + 1023) / 1024)  // 98

__global__ __launch_bounds__(128) void scan2(const int* __restrict__ bsum,
                                             int* __restrict__ boff) {
  __shared__ int sh[128];
  int t = threadIdx.x;
  int own = (t < NBLK1) ? bsum[t] : 0;
  sh[t] = own;
  __syncthreads();
  for (int off = 1; off < 128; off <<= 1) {
    int x = (t >= off) ? sh[t - off] : 0;
    __syncthreads();
    sh[t] += x;
    __syncthreads();
  }
  boff[t] = sh[t] - own;
}

__global__ __launch_bounds__(256) void scan3(int* __restrict__ rp,
                                             const int* __restrict__ boff,
                                             int* __restrict__ cursor) {
  int idx = blockIdx.x * 256 + threadIdx.x;
  if (idx < N_NODES) {
    int v = rp[idx] + boff[idx >> 10];
    rp[idx] = v;
    cursor[idx] = v;
  }
  if (idx == 0) rp[N_NODES] = TOT;
}

// scatter + fused edge-weight computation -> one 16B record {src, w01, w23, 0}
__global__ __launch_bounds__(256) void scatter_edges(const int* __restrict__ esrc,
                                                     const int* __restrict__ edst,
                                                     const float* __restrict__ as_buf,
                                                     const float* __restrict__ ad_buf,
                                                     int* __restrict__ cursor,
                                                     uint4* __restrict__ erec) {
  int e = blockIdx.x * 256 + threadIdx.x;
  if (e >= TOT) return;
  int s, d;
  if (e < N_EDGES) { s = esrc[e]; d = edst[e]; }
  else { s = e - N_EDGES; d = s; }
  int p = atomicAdd(&cursor[d], 1);
  float4 a1 = *reinterpret_cast<const float4*>(as_buf + (size_t)s * NHEAD);
  float4 a2 = *reinterpret_cast<const float4*>(ad_buf + (size_t)d * NHEAD);
  float e0 = a1.x + a2.x; e0 = e0 > 0.f ? e0 : NEG_SLOPE * e0;
  float e1 = a1.y + a2.y; e1 = e1 > 0.f ? e1 : NEG_SLOPE * e1;
  float e2 = a1.z + a2.z; e2 = e2 > 0.f ? e2 : NEG_SLOPE * e2;
  float e3 = a1.w + a2.w; e3 = e3 > 0.f ? e3 : NEG_SLOPE * e3;
  // exp(e-4): shift cancels in softmax ratio, keeps fp16 in safe range
  float w0 = __expf(e0 - 4.f), w1 = __expf(e1 - 4.f);
  float w2 = __expf(e2 - 4.f), w3 = __expf(e3 - 4.f);
  uint_t pk01 = __builtin_bit_cast(uint_t, __builtin_amdgcn_cvt_pkrtz(w0, w1));
  uint_t pk23 = __builtin_bit_cast(uint_t, __builtin_amdgcn_cvt_pkrtz(w2, w3));
  erec[p] = make_uint4((uint_t)s, pk01, pk23, 0u);
}

// ---------------- fused softmax + aggregation ----------------
// One wave per node; 4 edges per iteration (2 half-wave records in flight).
__global__ __launch_bounds__(256) void aggregate(const int* __restrict__ rp,
                                                 const uint4* __restrict__ erec,
                                                 const uint2* __restrict__ Hp,
                                                 const float* __restrict__ bias,
                                                 float* __restrict__ out) {
  int n = blockIdx.x * 4 + (threadIdx.x >> 6);
  int lane = threadIdx.x & 63;
  if (n >= N_NODES) return;
  const int half = lane >> 5;
  const uint_t off_lane = (uint_t)(lane & 31) << 4;  // byte offset within 512B row
  const char* __restrict__ Hb = (const char*)Hp;

  int beg = rp[n], end = rp[n + 1];  // end > beg (self-loop guaranteed)
  const int last = end - 1;

  float acc[8] = {};  // {chA,chB} x {h0..h3}
  float den[4] = {};

  int ia = beg + half;     if (ia > last) ia = last;
  int ib = beg + 2 + half; if (ib > last) ib = last;
  uint4 rec_a = erec[ia];
  uint4 rec_b = erec[ib];

  for (int j = beg; j < end; j += 4) {
    uint4 cur_a = rec_a;
    uint4 cur_b = rec_b;
    ia = j + 4 + half; if (ia > last) ia = last;
    ib = j + 6 + half; if (ib > last) ib = last;
    rec_a = erec[ia];
    rec_b = erec[ib];

    uint_t hoff_a = (cur_a.x << 9) | off_lane;
    uint_t hoff_b = (cur_b.x << 9) | off_lane;
    uint4 hva = *reinterpret_cast<const uint4*>(Hb + hoff_a);
    uint4 hvb = *reinterpret_cast<const uint4*>(Hb + hoff_b);

    bool act_a = (j + half) < end;
    bool act_b = (j + 2 + half) < end;
    uint_t wa01u = act_a ? cur_a.y : 0u;
    uint_t wa23u = act_a ? cur_a.z : 0u;
    uint_t wb01u = act_b ? cur_b.y : 0u;
    uint_t wb23u = act_b ? cur_b.z : 0u;

    h2v wa01 = __builtin_bit_cast(h2v, wa01u);
    h2v wa23 = __builtin_bit_cast(h2v, wa23u);
    h2v wb01 = __builtin_bit_cast(h2v, wb01u);
    h2v wb23 = __builtin_bit_cast(h2v, wb23u);

    h2v haa = __builtin_bit_cast(h2v, hva.x);
    h2v hab = __builtin_bit_cast(h2v, hva.y);
    h2v hac = __builtin_bit_cast(h2v, hva.z);
    h2v had = __builtin_bit_cast(h2v, hva.w);

    acc[0] += (float)wa01.x * (float)haa.x;
    acc[1] += (float)wa01.y * (float)haa.y;
    acc[2] += (float)wa23.x * (float)hab.x;
    acc[3] += (float)wa23.y * (float)hab.y;
    acc[4] += (float)wa01.x * (float)hac.x;
    acc[5] += (float)wa01.y * (float)hac.y;
    acc[6] += (float)wa23.x * (float)had.x;
    acc[7] += (float)wa23.y * (float)had.y;
    den[0] += (float)wa01.x;
    den[1] += (float)wa01.y;
    den[2] += (float)wa23.x;
    den[3] += (float)wa23.y;

    h2v hba = __builtin_bit_cast(h2v, hvb.x);
    h2v hbb = __builtin_bit_cast(h2v, hvb.y);
    h2v hbc = __builtin_bit_cast(h2v, hvb.z);
    h2v hbd = __builtin_bit_cast(h2v, hvb.w);

    acc[0] += (float)wb01.x * (float)hba.x;
    acc[1] += (float)wb01.y * (float)hba.y;
    acc[2] += (float)wb23.x * (float)hbb.x;
    acc[3] += (float)wb23.y * (float)hbb.y;
    acc[4] += (float)wb01.x * (float)hbc.x;
    acc[5] += (float)wb01.y * (float)hbc.y;
    acc[6] += (float)wb23.x * (float)hbd.x;
    acc[7] += (float)wb23.y * (float)hbd.y;
    den[0] += (float)wb01.x;
    den[1] += (float)wb01.y;
    den[2] += (float)wb23.x;
    den[3] += (float)wb23.y;
  }

#pragma unroll
  for (int k = 0; k < 8; ++k) acc[k] += __shfl_xor(acc[k], 32, 64);
#pragma unroll
  for (int k = 0; k < 4; ++k) den[k] += __shfl_xor(den[k], 32, 64);

  if (lane < 32) {
    float i0 = 1.f / (den[0] + 1e-30f);
    float i1 = 1.f / (den[1] + 1e-30f);
    float i2 = 1.f / (den[2] + 1e-30f);
    float i3 = 1.f / (den[3] + 1e-30f);
    float2 b2 = *reinterpret_cast<const float2*>(bias + 2 * lane);
    float rA = 0.25f * (acc[0] * i0 + acc[1] * i1 + acc[2] * i2 + acc[3] * i3) + b2.x;
    float rB = 0.25f * (acc[4] * i0 + acc[5] * i1 + acc[6] * i2 + acc[7] * i3) + b2.y;
    *reinterpret_cast<float2*>(out + (size_t)n * CH + 2 * lane) = make_float2(rA, rB);
  }
}

extern "C" void kernel_launch(void* const* d_in, const int* in_sizes, int n_in,
                              void* d_out, int out_size, void* d_ws, size_t ws_size,
                              hipStream_t stream) {
  const float* x       = (const float*)d_in[0];
  const int*   eidx    = (const int*)d_in[1];
  const float* W       = (const float*)d_in[2];
  const float* att_src = (const float*)d_in[3];
  const float* att_dst = (const float*)d_in[4];
  const float* bias    = (const float*)d_in[5];
  float* out = (float*)d_out;

  uint2* Hmp    = (uint2*)d_ws;                               // N*64 uint2 (51.2MB)
  uint4* erec   = (uint4*)(Hmp + (size_t)N_NODES * 64);       // TOT uint4 (27.2MB)
  float* as_buf = (float*)(erec + (size_t)TOT);               // N*4
  float* ad_buf = as_buf + (size_t)N_NODES * NHEAD;           // N*4
  uint4* Wt_arr = (uint4*)(ad_buf + (size_t)N_NODES * NHEAD); // 8192 uint4 (128KB)
  int*   deg    = (int*)(Wt_arr + 8192);                      // N (reused as cursor)
  int*   rp     = deg + N_NODES;                              // N+1
  int*   bsum   = rp + N_NODES + 1;                           // 128
  int*   boff   = bsum + 128;                                 // 128

  const int* esrc = eidx;
  const int* edst = eidx + N_EDGES;

  conv_w<<<32, 256, 0, stream>>>(W, Wt_arr);
  hipMemsetAsync(deg, 0, (size_t)N_NODES * sizeof(int), stream);
  count_deg<<<(N_EDGES / 4 + 255) / 256, 256, 0, stream>>>(edst, deg);

  gemm_mfma<<<256, 1024, 0, stream>>>(x, Wt_arr, att_src, att_dst, Hmp, as_buf, ad_buf, N_NODES);

  scan1<<<NBLK1, 256, 0, stream>>>(deg, rp, bsum);
  scan2<<<1, 128, 0, stream>>>(bsum, boff);
  scan3<<<(N_NODES + 255) / 256, 256, 0, stream>>>(rp, boff, deg /*cursor*/);
  scatter_edges<<<(TOT + 255) / 256, 256, 0, stream>>>(esrc, edst, as_buf, ad_buf,
                                                       deg /*cursor*/, erec);

  aggregate<<<(N_NODES + 3) / 4, 256, 0, stream>>>(rp, erec, Hmp, bias, out);
}

// Round 9
// 310.767 us; speedup vs baseline: 2.1266x; 2.1266x over previous
//
#include <hip/hip_runtime.h>

#define N_NODES 100000
#define N_EDGES 1600000
#define TOT (N_EDGES + N_NODES)
#define IN_CH 256
#define NHEAD 4
#define CH 64
#define HC 256
#define NEG_SLOPE 0.2f

typedef _Float16 half8 __attribute__((ext_vector_type(8)));
typedef _Float16 h2v __attribute__((ext_vector_type(2)));
typedef float f32x4 __attribute__((ext_vector_type(4)));
typedef unsigned short ushort_t;
typedef unsigned int uint_t;

static __device__ __forceinline__ ushort_t f2h(float f) {
  _Float16 h = (_Float16)f;
  return __builtin_bit_cast(ushort_t, h);
}

// async global->LDS, 16B per lane (dest must be wave-uniform base + lane*16)
static __device__ __forceinline__ void gload_lds16(const char* g, char* l) {
  __builtin_amdgcn_global_load_lds(
      (const __attribute__((address_space(1))) unsigned int*)g,
      (__attribute__((address_space(3))) unsigned int*)l, 16, 0, 0);
}

// ---------------- W fp32 [K=256][N=256] -> Wt_arr, MFMA-fragment-major ----------------
// uint4 index f = (ks*16 + n)*64 + lane ; halfs j=0..7 :
//   W[ ks*32 + (lane>>4)*8 + j ][ n*16 + (lane&15) ]
__global__ __launch_bounds__(256) void conv_w(const float* __restrict__ W,
                                              uint4* __restrict__ Wt_arr) {
  int id = blockIdx.x * 256 + threadIdx.x;  // 0..8191
  int lane = id & 63;
  int n = (id >> 6) & 15;
  int ks = id >> 10;
  int col = n * 16 + (lane & 15);
  int kbase = ks * 32 + (lane >> 4) * 8;
  ushort_t h[8];
#pragma unroll
  for (int j = 0; j < 8; ++j) h[j] = f2h(W[(size_t)(kbase + j) * HC + col]);
  uint4 u;
  u.x = (uint_t)h[0] | ((uint_t)h[1] << 16);
  u.y = (uint_t)h[2] | ((uint_t)h[3] << 16);
  u.z = (uint_t)h[4] | ((uint_t)h[5] << 16);
  u.w = (uint_t)h[6] | ((uint_t)h[7] << 16);
  Wt_arr[id] = u;
}

// ---------------- 2-phase double-buffered MFMA GEMM + fused attn dots + deg count ----
// 256 threads = 4 waves; block covers 64 rows; wave = 16 rows x 256 cols.
__global__ __launch_bounds__(256) void gemm_mfma(const float* __restrict__ X,
                                                 const uint4* __restrict__ Wt_arr,
                                                 const float* __restrict__ att_src,
                                                 const float* __restrict__ att_dst,
                                                 uint2* __restrict__ Hmp,
                                                 float* __restrict__ as_out,
                                                 float* __restrict__ ad_out,
                                                 const int* __restrict__ edst,
                                                 int* __restrict__ deg, int M) {
  __shared__ uint4 Bs[2][1024];               // 2 x 16 KB, [n*64+lane] linear
  __shared__ __align__(16) ushort_t As[2][64][40];  // 2 x 5 KB, +8 pad halfs
  const int tid = threadIdx.x;
  const int lane = tid & 63;
  const int wid = tid >> 6;
  const int l16 = lane & 15;
  const int lhi = lane >> 4;
  const int row0 = blockIdx.x * 64;

  // A-stage mapping: thread t -> row t>>2, 8 floats at col (t&3)*8
  const int arow = tid >> 2;
  const int acol = (tid & 3) * 8;
  int growA = row0 + arow; if (growA >= M) growA = M - 1;
  const float* __restrict__ xsrc = X + (size_t)growA * IN_CH + acol;

  const char* __restrict__ wbase = (const char*)Wt_arr;
  char* bdst0 = (char*)&Bs[0][0] + tid * 16;
  char* bdst1 = (char*)&Bs[1][0] + tid * 16;

  f32x4 acc[16] = {};

  // prologue: stage k-step 0 into buffer 0
  {
    const char* bsrc = wbase + tid * 16;
    gload_lds16(bsrc,         bdst0);
    gload_lds16(bsrc + 4096,  bdst0 + 4096);
    gload_lds16(bsrc + 8192,  bdst0 + 8192);
    gload_lds16(bsrc + 12288, bdst0 + 12288);
    float4 xa = *reinterpret_cast<const float4*>(xsrc);
    float4 xb = *reinterpret_cast<const float4*>(xsrc + 4);
    uint4 ua;
    ua.x = __builtin_bit_cast(uint_t, __builtin_amdgcn_cvt_pkrtz(xa.x, xa.y));
    ua.y = __builtin_bit_cast(uint_t, __builtin_amdgcn_cvt_pkrtz(xa.z, xa.w));
    ua.z = __builtin_bit_cast(uint_t, __builtin_amdgcn_cvt_pkrtz(xb.x, xb.y));
    ua.w = __builtin_bit_cast(uint_t, __builtin_amdgcn_cvt_pkrtz(xb.z, xb.w));
    *reinterpret_cast<uint4*>(&As[0][arow][acol]) = ua;
  }

  int cur = 0;
#pragma unroll
  for (int ks = 0; ks < 8; ++ks) {
    __syncthreads();  // drains vmcnt (B DMA) + lgkmcnt (A ds_write) of prev stage

    // issue next-tile loads EARLY (B via LDS-DMA, A into regs)
    float4 xa, xb;
    if (ks < 7) {
      char* bd = (cur == 0) ? bdst1 : bdst0;
      const char* bsrc = wbase + (ks + 1) * 16384 + tid * 16;
      gload_lds16(bsrc,         bd);
      gload_lds16(bsrc + 4096,  bd + 4096);
      gload_lds16(bsrc + 8192,  bd + 8192);
      gload_lds16(bsrc + 12288, bd + 12288);
      xa = *reinterpret_cast<const float4*>(xsrc + (ks + 1) * 32);
      xb = *reinterpret_cast<const float4*>(xsrc + (ks + 1) * 32 + 4);
    }

    // compute current k-step (hides the loads just issued)
    half8 a = *reinterpret_cast<const half8*>(&As[cur][wid * 16 + l16][lhi * 8]);
    const char* bbase = (const char*)&Bs[cur][0];
#pragma unroll
    for (int n = 0; n < 16; ++n) {
      half8 b = *reinterpret_cast<const half8*>(bbase + n * 1024 + lane * 16);
      acc[n] = __builtin_amdgcn_mfma_f32_16x16x32_f16(a, b, acc[n], 0, 0, 0);
    }

    // write A LATE into the next buffer
    if (ks < 7) {
      uint4 ua;
      ua.x = __builtin_bit_cast(uint_t, __builtin_amdgcn_cvt_pkrtz(xa.x, xa.y));
      ua.y = __builtin_bit_cast(uint_t, __builtin_amdgcn_cvt_pkrtz(xa.z, xa.w));
      ua.z = __builtin_bit_cast(uint_t, __builtin_amdgcn_cvt_pkrtz(xb.x, xb.y));
      ua.w = __builtin_bit_cast(uint_t, __builtin_amdgcn_cvt_pkrtz(xb.z, xb.w));
      *reinterpret_cast<uint4*>(&As[cur ^ 1][arow][acol]) = ua;
    }
    cur ^= 1;
  }

  // epilogue: pack Hmp + fused attention dots
  float attS[16], attD[16];
#pragma unroll
  for (int n = 0; n < 16; ++n) {
    attS[n] = att_src[n * 16 + l16];
    attD[n] = att_dst[n * 16 + l16];
  }

#pragma unroll
  for (int r = 0; r < 4; ++r) {
    int grow = row0 + wid * 16 + lhi * 4 + r;
    if (grow < M) {
#pragma unroll
      for (int n2 = 0; n2 < 4; ++n2) {
        uint_t pk01 = __builtin_bit_cast(uint_t,
            __builtin_amdgcn_cvt_pkrtz(acc[n2][r], acc[n2 + 4][r]));
        uint_t pk23 = __builtin_bit_cast(uint_t,
            __builtin_amdgcn_cvt_pkrtz(acc[n2 + 8][r], acc[n2 + 12][r]));
        Hmp[(size_t)grow * 64 + n2 * 16 + l16] = make_uint2(pk01, pk23);
      }
      float sv[4] = {0.f, 0.f, 0.f, 0.f}, dv[4] = {0.f, 0.f, 0.f, 0.f};
#pragma unroll
      for (int h = 0; h < 4; ++h)
#pragma unroll
        for (int j = 0; j < 4; ++j) {
          sv[h] += acc[h * 4 + j][r] * attS[h * 4 + j];
          dv[h] += acc[h * 4 + j][r] * attD[h * 4 + j];
        }
#pragma unroll
      for (int off = 1; off < 16; off <<= 1)
#pragma unroll
        for (int h = 0; h < 4; ++h) {
          sv[h] += __shfl_xor(sv[h], off, 16);
          dv[h] += __shfl_xor(dv[h], off, 16);
        }
      if (l16 == 0) {
#pragma unroll
        for (int h = 0; h < 4; ++h) {
          as_out[(size_t)grow * 4 + h] = sv[h];
          ad_out[(size_t)grow * 4 + h] = dv[h];
        }
      }
    }
  }

  // fused degree count tail (rides in idle memory slack; R6-verified)
  {
    int t = blockIdx.x * 256 + tid;
    if (t < N_EDGES / 4) {
      int4 d4 = reinterpret_cast<const int4*>(edst)[t];
      atomicAdd(&deg[d4.x], 1);
      atomicAdd(&deg[d4.y], 1);
      atomicAdd(&deg[d4.z], 1);
      atomicAdd(&deg[d4.w], 1);
    }
  }
}

// ---------------- CSR build (scans; scan1 adds +1 self-loop inline) ----------------
__global__ __launch_bounds__(256) void scan1(const int* __restrict__ deg,
                                             int* __restrict__ rp,
                                             int* __restrict__ bsum) {
  __shared__ int sh[256];
  int t = threadIdx.x;
  int base = blockIdx.x * 1024 + t * 4;
  int v[4];
#pragma unroll
  for (int i = 0; i < 4; ++i) v[i] = (base + i < N_NODES) ? (deg[base + i] + 1) : 0;
  int tsum = v[0] + v[1] + v[2] + v[3];
  sh[t] = tsum;
  __syncthreads();
  for (int off = 1; off < 256; off <<= 1) {
    int x = (t >= off) ? sh[t - off] : 0;
    __syncthreads();
    sh[t] += x;
    __syncthreads();
  }
  if (t == 255) bsum[blockIdx.x] = sh[255];
  int run = sh[t] - tsum;
#pragma unroll
  for (int i = 0; i < 4; ++i) {
    if (base + i < N_NODES) rp[base + i] = run;
    run += v[i];
  }
}

#define NBLK1 ((N_NODES + 1023) / 1024)  // 98

__global__ __launch_bounds__(128) void scan2(const int* __restrict__ bsum,
                                             int* __restrict__ boff) {
  __shared__ int sh[128];
  int t = threadIdx.x;
  int own = (t < NBLK1) ? bsum[t] : 0;
  sh[t] = own;
  __syncthreads();
  for (int off = 1; off < 128; off <<= 1) {
    int x = (t >= off) ? sh[t - off] : 0;
    __syncthreads();
    sh[t] += x;
    __syncthreads();
  }
  boff[t] = sh[t] - own;
}

__global__ __launch_bounds__(256) void scan3(int* __restrict__ rp,
                                             const int* __restrict__ boff,
                                             int* __restrict__ cursor) {
  int idx = blockIdx.x * 256 + threadIdx.x;
  if (idx < N_NODES) {
    int v = rp[idx] + boff[idx >> 10];
    rp[idx] = v;
    cursor[idx] = v;
  }
  if (idx == 0) rp[N_NODES] = TOT;
}

// scatter + fused edge-weight computation -> one 16B record {src, w01, w23, 0}
__global__ __launch_bounds__(256) void scatter_edges(const int* __restrict__ esrc,
                                                     const int* __restrict__ edst,
                                                     const float* __restrict__ as_buf,
                                                     const float* __restrict__ ad_buf,
                                                     int* __restrict__ cursor,
                                                     uint4* __restrict__ erec) {
  int e = blockIdx.x * 256 + threadIdx.x;
  if (e >= TOT) return;
  int s, d;
  if (e < N_EDGES) { s = esrc[e]; d = edst[e]; }
  else { s = e - N_EDGES; d = s; }
  int p = atomicAdd(&cursor[d], 1);
  float4 a1 = *reinterpret_cast<const float4*>(as_buf + (size_t)s * NHEAD);
  float4 a2 = *reinterpret_cast<const float4*>(ad_buf + (size_t)d * NHEAD);
  float e0 = a1.x + a2.x; e0 = e0 > 0.f ? e0 : NEG_SLOPE * e0;
  float e1 = a1.y + a2.y; e1 = e1 > 0.f ? e1 : NEG_SLOPE * e1;
  float e2 = a1.z + a2.z; e2 = e2 > 0.f ? e2 : NEG_SLOPE * e2;
  float e3 = a1.w + a2.w; e3 = e3 > 0.f ? e3 : NEG_SLOPE * e3;
  // exp(e-4): shift cancels in softmax ratio, keeps fp16 in safe range
  float w0 = __expf(e0 - 4.f), w1 = __expf(e1 - 4.f);
  float w2 = __expf(e2 - 4.f), w3 = __expf(e3 - 4.f);
  uint_t pk01 = __builtin_bit_cast(uint_t, __builtin_amdgcn_cvt_pkrtz(w0, w1));
  uint_t pk23 = __builtin_bit_cast(uint_t, __builtin_amdgcn_cvt_pkrtz(w2, w3));
  erec[p] = make_uint4((uint_t)s, pk01, pk23, 0u);
}

// ---------------- fused softmax + aggregation ----------------
// One wave per node; 4 edges per iteration (2 half-wave records in flight).
__global__ __launch_bounds__(256) void aggregate(const int* __restrict__ rp,
                                                 const uint4* __restrict__ erec,
                                                 const uint2* __restrict__ Hp,
                                                 const float* __restrict__ bias,
                                                 float* __restrict__ out) {
  int n = blockIdx.x * 4 + (threadIdx.x >> 6);
  int lane = threadIdx.x & 63;
  if (n >= N_NODES) return;
  const int half = lane >> 5;
  const uint_t off_lane = (uint_t)(lane & 31) << 4;
  const char* __restrict__ Hb = (const char*)Hp;

  int beg = rp[n], end = rp[n + 1];
  const int last = end - 1;

  float acc[8] = {};
  float den[4] = {};

  int ia = beg + half;     if (ia > last) ia = last;
  int ib = beg + 2 + half; if (ib > last) ib = last;
  uint4 rec_a = erec[ia];
  uint4 rec_b = erec[ib];

  for (int j = beg; j < end; j += 4) {
    uint4 cur_a = rec_a;
    uint4 cur_b = rec_b;
    ia = j + 4 + half; if (ia > last) ia = last;
    ib = j + 6 + half; if (ib > last) ib = last;
    rec_a = erec[ia];
    rec_b = erec[ib];

    uint_t hoff_a = (cur_a.x << 9) | off_lane;
    uint_t hoff_b = (cur_b.x << 9) | off_lane;
    uint4 hva = *reinterpret_cast<const uint4*>(Hb + hoff_a);
    uint4 hvb = *reinterpret_cast<const uint4*>(Hb + hoff_b);

    bool act_a = (j + half) < end;
    bool act_b = (j + 2 + half) < end;
    uint_t wa01u = act_a ? cur_a.y : 0u;
    uint_t wa23u = act_a ? cur_a.z : 0u;
    uint_t wb01u = act_b ? cur_b.y : 0u;
    uint_t wb23u = act_b ? cur_b.z : 0u;

    h2v wa01 = __builtin_bit_cast(h2v, wa01u);
    h2v wa23 = __builtin_bit_cast(h2v, wa23u);
    h2v wb01 = __builtin_bit_cast(h2v, wb01u);
    h2v wb23 = __builtin_bit_cast(h2v, wb23u);

    h2v haa = __builtin_bit_cast(h2v, hva.x);
    h2v hab = __builtin_bit_cast(h2v, hva.y);
    h2v hac = __builtin_bit_cast(h2v, hva.z);
    h2v had = __builtin_bit_cast(h2v, hva.w);

    acc[0] += (float)wa01.x * (float)haa.x;
    acc[1] += (float)wa01.y * (float)haa.y;
    acc[2] += (float)wa23.x * (float)hab.x;
    acc[3] += (float)wa23.y * (float)hab.y;
    acc[4] += (float)wa01.x * (float)hac.x;
    acc[5] += (float)wa01.y * (float)hac.y;
    acc[6] += (float)wa23.x * (float)had.x;
    acc[7] += (float)wa23.y * (float)had.y;
    den[0] += (float)wa01.x;
    den[1] += (float)wa01.y;
    den[2] += (float)wa23.x;
    den[3] += (float)wa23.y;

    h2v hba = __builtin_bit_cast(h2v, hvb.x);
    h2v hbb = __builtin_bit_cast(h2v, hvb.y);
    h2v hbc = __builtin_bit_cast(h2v, hvb.z);
    h2v hbd = __builtin_bit_cast(h2v, hvb.w);

    acc[0] += (float)wb01.x * (float)hba.x;
    acc[1] += (float)wb01.y * (float)hba.y;
    acc[2] += (float)wb23.x * (float)hbb.x;
    acc[3] += (float)wb23.y * (float)hbb.y;
    acc[4] += (float)wb01.x * (float)hbc.x;
    acc[5] += (float)wb01.y * (float)hbc.y;
    acc[6] += (float)wb23.x * (float)hbd.x;
    acc[7] += (float)wb23.y * (float)hbd.y;
    den[0] += (float)wb01.x;
    den[1] += (float)wb01.y;
    den[2] += (float)wb23.x;
    den[3] += (float)wb23.y;
  }

#pragma unroll
  for (int k = 0; k < 8; ++k) acc[k] += __shfl_xor(acc[k], 32, 64);
#pragma unroll
  for (int k = 0; k < 4; ++k) den[k] += __shfl_xor(den[k], 32, 64);

  if (lane < 32) {
    float i0 = 1.f / (den[0] + 1e-30f);
    float i1 = 1.f / (den[1] + 1e-30f);
    float i2 = 1.f / (den[2] + 1e-30f);
    float i3 = 1.f / (den[3] + 1e-30f);
    float2 b2 = *reinterpret_cast<const float2*>(bias + 2 * lane);
    float rA = 0.25f * (acc[0] * i0 + acc[1] * i1 + acc[2] * i2 + acc[3] * i3) + b2.x;
    float rB = 0.25f * (acc[4] * i0 + acc[5] * i1 + acc[6] * i2 + acc[7] * i3) + b2.y;
    *reinterpret_cast<float2*>(out + (size_t)n * CH + 2 * lane) = make_float2(rA, rB);
  }
}

extern "C" void kernel_launch(void* const* d_in, const int* in_sizes, int n_in,
                              void* d_out, int out_size, void* d_ws, size_t ws_size,
                              hipStream_t stream) {
  const float* x       = (const float*)d_in[0];
  const int*   eidx    = (const int*)d_in[1];
  const float* W       = (const float*)d_in[2];
  const float* att_src = (const float*)d_in[3];
  const float* att_dst = (const float*)d_in[4];
  const float* bias    = (const float*)d_in[5];
  float* out = (float*)d_out;

  uint2* Hmp    = (uint2*)d_ws;                               // N*64 uint2 (51.2MB)
  uint4* erec   = (uint4*)(Hmp + (size_t)N_NODES * 64);       // TOT uint4 (27.2MB)
  float* as_buf = (float*)(erec + (size_t)TOT);               // N*4
  float* ad_buf = as_buf + (size_t)N_NODES * NHEAD;           // N*4
  uint4* Wt_arr = (uint4*)(ad_buf + (size_t)N_NODES * NHEAD); // 8192 uint4 (128KB)
  int*   deg    = (int*)(Wt_arr + 8192);                      // N (reused as cursor)
  int*   rp     = deg + N_NODES;                              // N+1
  int*   bsum   = rp + N_NODES + 1;                           // 128
  int*   boff   = bsum + 128;                                 // 128

  const int* esrc = eidx;
  const int* edst = eidx + N_EDGES;

  conv_w<<<32, 256, 0, stream>>>(W, Wt_arr);
  hipMemsetAsync(deg, 0, (size_t)N_NODES * sizeof(int), stream);

  dim3 ggrid((N_NODES + 63) / 64);  // 1563 blocks; also covers N_EDGES/4 int4 deg-counts
  gemm_mfma<<<ggrid, 256, 0, stream>>>(x, Wt_arr, att_src, att_dst, Hmp, as_buf, ad_buf,
                                       edst, deg, N_NODES);

  scan1<<<NBLK1, 256, 0, stream>>>(deg, rp, bsum);
  scan2<<<1, 128, 0, stream>>>(bsum, boff);
  scan3<<<(N_NODES + 255) / 256, 256, 0, stream>>>(rp, boff, deg /*cursor*/);
  scatter_edges<<<(TOT + 255) / 256, 256, 0, stream>>>(esrc, edst, as_buf, ad_buf,
                                                       deg /*cursor*/, erec);

  aggregate<<<(N_NODES + 3) / 4, 256, 0, stream>>>(rp, erec, Hmp, bias, out);
}